// Round 6
// baseline (128.007 us; speedup 1.0000x reference)
//
#include <hip/hip_runtime.h>
#include <math.h>

#ifndef M_PI
#define M_PI 3.14159265358979323846
#endif

#define DMODEL 256
#define NSTATE 64
#define LSEQ   8192
#define INVL   (1.0f/8192.0f)

// Workspace layout (bytes).
#define OFF_TW  0                                  // float2[6144]: e^{+2pi i j/L}
#define OFF_DN  (6144*8)                           // float4[3*DMODEL*NSTATE] compact
#define OFF_CDT (OFF_DN + DMODEL*NSTATE*48)        // float[DMODEL]: 2/dt
#define OFF_XY  (OFF_CDT + 1024)                   // float2[DMODEL*LSEQ]: stage-4 output
#define WS_NEED ((size_t)OFF_XY + (size_t)DMODEL*LSEQ*8)   // ~17.6 MB

__device__ __forceinline__ float sin_rev(float r) {
#if __has_builtin(__builtin_amdgcn_sinf)
  return __builtin_amdgcn_sinf(r);        // D = sin(S0 * 2pi), input in revolutions
#else
  return __sinf(r * 6.283185307179586f);
#endif
}
__device__ __forceinline__ float cos_rev(float r) {
#if __has_builtin(__builtin_amdgcn_cosf)
  return __builtin_amdgcn_cosf(r);
#else
  return __cosf(r * 6.283185307179586f);
#endif
}

__device__ __forceinline__ float2 cmul(float2 a, float2 b) {
  return make_float2(a.x*b.x - a.y*b.y, a.x*b.y + a.y*b.x);
}

// K_hat/L from the 4 complex sums. PRB*BRP = (S1+iS2)(S1-iS2) = S1^2 + S2^2.
// Prefactor 2/(1+z) = 1 + i*T; fold 1/L here.
__device__ __forceinline__ float2 woodbury(float2 S1, float2 S2, float2 S3,
                                           float2 S4, float T) {
  float nr = (S1.x*S1.x - S1.y*S1.y) + (S2.x*S2.x - S2.y*S2.y);
  float ni = 2.0f*(S1.x*S1.y + S2.x*S2.y);
  float dr = 1.0f + S3.x, di = S3.y;
  float inv = __builtin_amdgcn_rcpf(fmaf(dr, dr, di*di));
  float qr = (nr*dr + ni*di) * inv;
  float qi = (ni*dr - nr*di) * inv;
  float vr = S4.x - qr, vi = S4.y - qi;
  return make_float2((vr - T*vi)*INVL, (vi + T*vr)*INVL);
}

// Radix-4 DIT butterfly (inverse transform, W = e^{+2pi i/L}).
__device__ __forceinline__ void radix4(float2& x0, float2& x1, float2& x2, float2& x3,
                                       float2 w1, float2 w2, float2 w3) {
  const float2 t1 = cmul(w1, x1);
  const float2 t2 = cmul(w2, x2);
  const float2 t3 = cmul(w3, x3);
  const float2 u0 = make_float2(x0.x + t2.x, x0.y + t2.y);
  const float2 u1 = make_float2(x0.x - t2.x, x0.y - t2.y);
  const float2 u2 = make_float2(t1.x + t3.x, t1.y + t3.y);
  const float2 vv = make_float2(t1.x - t3.x, t1.y - t3.y);
  x0 = make_float2(u0.x + u2.x, u0.y + u2.y);   // Y0
  x1 = make_float2(u1.x - vv.y, u1.y + vv.x);   // Y1 = u1 + i*vv
  x2 = make_float2(u0.x - u2.x, u0.y - u2.y);   // Y2
  x3 = make_float2(u1.x + vv.y, u1.y - vv.x);   // Y3 = u1 - i*vv
}

// One (kA, kA+4096) pair: Cauchy sums + Woodbury + radix-2 fold.
// Scalar 11-op/point inner body: dim = lim - gIm makes Im R = +dim*inv, so all
// 8 accumulations use positively-stored weights; Re R = sp*inv is folded into
// the (w*sp) weights. Table (3 x float4 per n, wave-uniform -> s_load):
//   q0 = (lim, sp^2, w1r*sp, w1i*sp)
//   q1 = (w2*sp, w3*sp, w1r, w1i)
//   q2 = (w2, w3, -, -)
__device__ __forceinline__ float4 cauchy_pair(const float4* __restrict__ dnp,
                                              const float c, const int b) {
  const unsigned p = (unsigned)(2*b);
  const unsigned r = __brev(p) >> 19;       // 13-bit reversal
  const int kA = (int)((r & 0x1000u) | ((r & 0x0555u) << 1) | ((r & 0x0AAAu) >> 1));
  // kA < 4096. T = tan(pi k / L); (1-z)/(1+z) = i*T exactly (no cancellation).
  const float rev = (float)kA * (1.0f/16384.0f);
  const float sA = sin_rev(rev), cA = cos_rev(rev);
  float TA = sA * __builtin_amdgcn_rcpf(cA);
  float TB = -cA * __builtin_amdgcn_rcpf(sA);    // tan(x + pi/2) = -cot(x)
  TA = fminf(fmaxf(TA, -1e7f), 1e7f);
  TB = fminf(fmaxf(TB, -1e7f), 1e7f);
  const float gA = c * TA, gB = c * TB;     // g = i*gIm, purely imaginary

  float2 s1a={0,0}, s2a={0,0}, s3a={0,0}, s4a={0,0};
  float2 s1b={0,0}, s2b={0,0}, s3b={0,0}, s4b={0,0};
#pragma unroll 2
  for (int n = 0; n < NSTATE; ++n) {
    const float4 q0 = dnp[3*n];
    const float4 q1 = dnp[3*n+1];
    const float4 q2 = dnp[3*n+2];
    {
      const float dim = q0.x - gA;                            // lim - gIm
      const float inv = __builtin_amdgcn_rcpf(fmaf(dim, dim, q0.y));
      const float v = dim * inv;                              // Im R
      s1a.x = fmaf(q0.z, inv, s1a.x);  s1a.y = fmaf(q1.z, v, s1a.y);
      s2a.x = fmaf(q0.w, inv, s2a.x);  s2a.y = fmaf(q1.w, v, s2a.y);
      s3a.x = fmaf(q1.x, inv, s3a.x);  s3a.y = fmaf(q2.x, v, s3a.y);
      s4a.x = fmaf(q1.y, inv, s4a.x);  s4a.y = fmaf(q2.y, v, s4a.y);
    }
    {
      const float dim = q0.x - gB;
      const float inv = __builtin_amdgcn_rcpf(fmaf(dim, dim, q0.y));
      const float v = dim * inv;
      s1b.x = fmaf(q0.z, inv, s1b.x);  s1b.y = fmaf(q1.z, v, s1b.y);
      s2b.x = fmaf(q0.w, inv, s2b.x);  s2b.y = fmaf(q1.w, v, s2b.y);
      s3b.x = fmaf(q1.x, inv, s3b.x);  s3b.y = fmaf(q2.x, v, s3b.y);
      s4b.x = fmaf(q1.y, inv, s4b.x);  s4b.y = fmaf(q2.y, v, s4b.y);
    }
  }
  const float2 KA = woodbury(s1a, s2a, s3a, s4a, TA);
  const float2 KB = woodbury(s1b, s2b, s3b, s4b, TB);
  return make_float4(KA.x + KB.x, KA.y + KB.y, KA.x - KB.x, KA.y - KB.y);
}

// ---------------------------------------------------------------- precompute
__global__ __launch_bounds__(256) void precompute_kernel(
    const float* __restrict__ Lre, const float* __restrict__ Lim,
    const float* __restrict__ Pre, const float* __restrict__ Pim,
    const float* __restrict__ Bre, const float* __restrict__ Bim,
    const float* __restrict__ log_dt, char* __restrict__ ws)
{
  const int t = blockIdx.x * blockDim.x + threadIdx.x;  // 0..16383
  float2* tw  = (float2*)(ws + OFF_TW);
  float4* dn  = (float4*)(ws + OFF_DN);
  float*  cdt = (float*)(ws + OFF_CDT);

  if (t < 6144) {
    double th = (2.0 * M_PI / (double)LSEQ) * (double)t;
    double s, c; sincos(th, &s, &c);
    tw[t] = make_float2((float)c, (float)s);
  }
  {
    float lre = Lre[t], lim = Lim[t];
    float pre = Pre[t], pim = Pim[t];
    float bre = Bre[t], bim = Bim[t];
    float sp = fmaxf(lre, 0.0f) + log1pf(expf(-fabsf(lre)));  // softplus
    float w1r = pre*bre + pim*bim;   // Re conj(P)*B
    float w1i = pre*bim - pim*bre;   // Im conj(P)*B
    float w2  = pre*pre + pim*pim;   // |P|^2
    float w3  = bre*bre + bim*bim;   // |B|^2
    dn[3*t]   = make_float4(lim, sp*sp, w1r*sp, w1i*sp);
    dn[3*t+1] = make_float4(w2*sp, w3*sp, w1r, w1i);
    dn[3*t+2] = make_float4(w2, w3, 0.0f, 0.0f);
  }
  if (t < DMODEL) cdt[t] = 2.0f * expf(-log_dt[t]);
}

// ---------------------------------------------------------------- kernel A
// Cauchy + FFT stages 0..4 per (d, 2048-point segment). Radix-4 stage s only
// spans 4h = 2^(3+2s) elements, so stages 0..4 are segment-local. 512 threads,
// 16 KB LDS, launch_bounds(512,8) -> 4 blocks/CU = 8 waves/SIMD (2x the fused
// kernel's occupancy). Stage 4 writes complex results straight to workspace.
__global__ __launch_bounds__(512, 8) void cauchyfft_kernel(
    const float4* __restrict__ dn_all, const float* __restrict__ cdt,
    const float2* __restrict__ tw, float2* __restrict__ xy_ws)
{
  __shared__ __align__(16) float2 xy[2048];   // 16 KB
  const int d   = blockIdx.x >> 2;
  const int seg = blockIdx.x & 3;
  const int t   = threadIdx.x;                // 0..511
  const float c = cdt[d];                     // 2/dt, wave-uniform
  const float4* dnp = dn_all + (size_t)d * (3*NSTATE);

  // Phase 1: 1024 pairs per segment, 2 per thread (1 live at a time: ~40 VGPR).
#pragma unroll
  for (int pass = 0; pass < 2; ++pass) {
    const int bl = t + (pass << 9);           // local pair 0..1023
    ((float4*)xy)[bl] = cauchy_pair(dnp, c, (seg << 10) + bl);
  }
  __syncthreads();

  // Stages 0..3 in LDS (h = 2, 8, 32, 128), 512 butterflies each = 1/thread.
#pragma unroll
  for (int s = 0; s < 4; ++s) {
    const int h = 2 << (2*s);
    const int twsh = 10 - 2*s;
    const int pos = t & (h - 1);
    const int i0 = ((t >> (1 + 2*s)) << (3 + 2*s)) + pos;
    const int ti = pos << twsh;
    float2 x0 = xy[i0], x1 = xy[i0 + h], x2 = xy[i0 + 2*h], x3 = xy[i0 + 3*h];
    radix4(x0, x1, x2, x3, tw[ti], tw[2*ti], tw[3*ti]);
    xy[i0] = x0; xy[i0 + h] = x1; xy[i0 + 2*h] = x2; xy[i0 + 3*h] = x3;
    __syncthreads();
  }

  // Stage 4 (h = 512): read LDS, write complex to workspace (coalesced).
  {
    const int ti = t << 2;                    // twsh = 2
    float2 x0 = xy[t], x1 = xy[t + 512], x2 = xy[t + 1024], x3 = xy[t + 1536];
    radix4(x0, x1, x2, x3, tw[ti], tw[2*ti], tw[3*ti]);
    float2* xg = xy_ws + (size_t)d * LSEQ + (seg << 11);
    xg[t] = x0; xg[t + 512] = x1; xg[t + 1024] = x2; xg[t + 1536] = x3;
  }
}

// ---------------------------------------------------------------- kernel B
// Final stage 5 (span 8192, cross-segment) + real store. Pure streaming:
// 16.8 MB read (L3-resident) + 8.4 MB write, no LDS, no barriers.
__global__ __launch_bounds__(256) void finish_kernel(
    const float2* __restrict__ xy_ws, const float2* __restrict__ tw,
    const float* __restrict__ Din, float* __restrict__ out)
{
  const int d   = blockIdx.x >> 3;
  const int pos = ((blockIdx.x & 7) << 8) + threadIdx.x;   // 0..2047
  const float2* xr = xy_ws + (size_t)d * LSEQ;
  const float2 x0 = xr[pos];
  const float2 x1 = xr[pos + 2048];
  const float2 x2 = xr[pos + 4096];
  const float2 x3 = xr[pos + 6144];
  const float2 w1 = tw[pos], w2 = tw[2*pos], w3 = tw[3*pos];
  // Only real parts of Y are needed.
  const float t1x = w1.x*x1.x - w1.y*x1.y, t1y = w1.x*x1.y + w1.y*x1.x;
  const float t2x = w2.x*x2.x - w2.y*x2.y;
  const float t3x = w3.x*x3.x - w3.y*x3.y, t3y = w3.x*x3.y + w3.y*x3.x;
  const float u0 = x0.x + t2x, u1 = x0.x - t2x;
  const float u2 = t1x + t3x, vy = t1y - t3y;
  float* orow = out + (size_t)d * LSEQ;
  orow[pos]        = u0 + u2;     // Y0.x
  orow[pos + 2048] = u1 - vy;     // Y1.x
  orow[pos + 4096] = u0 - u2;     // Y2.x
  orow[pos + 6144] = u1 + vy;     // Y3.x

  // second tuple output: D passthrough (zeros buffer)
  if (blockIdx.x == 0) out[(size_t)DMODEL * LSEQ + threadIdx.x] =
      (threadIdx.x < DMODEL) ? Din[threadIdx.x] : 0.0f;
}

// ---------------------------------------------------------------- fused fallback
// Used only if ws_size < WS_NEED. Same math, single-kernel (R0 structure).
__global__ __launch_bounds__(1024) void fused_kernel(
    const float4* __restrict__ dn_all, const float* __restrict__ cdt,
    const float2* __restrict__ tw, const float* __restrict__ Din,
    float* __restrict__ out)
{
  __shared__ __align__(16) float2 xy[LSEQ];   // 64 KB
  const int d = blockIdx.x;
  const int t = threadIdx.x;                  // 0..1023
  const float c = cdt[d];
  const float4* dnp = dn_all + (size_t)d * (3*NSTATE);

  for (int j = 0; j < 4; ++j) {
    const int b = t + (j << 10);
    ((float4*)xy)[b] = cauchy_pair(dnp, c, b);
  }
  __syncthreads();

#pragma unroll
  for (int s = 0; s < 6; ++s) {
    const int h = 2 << (2*s);
    const int twsh = 10 - 2*s;
#pragma unroll
    for (int j = 0; j < 2; ++j) {
      const int bb = t + (j << 10);
      const int pos = bb & (h - 1);
      const int i0 = ((bb >> (1 + 2*s)) << (3 + 2*s)) + pos;
      const int ti = pos << twsh;
      float2 x0 = xy[i0], x1 = xy[i0 + h], x2 = xy[i0 + 2*h], x3 = xy[i0 + 3*h];
      radix4(x0, x1, x2, x3, tw[ti], tw[2*ti], tw[3*ti]);
      xy[i0] = x0; xy[i0 + h] = x1; xy[i0 + 2*h] = x2; xy[i0 + 3*h] = x3;
    }
    __syncthreads();
  }

  float* orow = out + (size_t)d * LSEQ;
  for (int i = t; i < LSEQ; i += 1024) orow[i] = xy[i].x;
  if (d == 0 && t < DMODEL) out[(size_t)DMODEL * LSEQ + t] = Din[t];
}

// ---------------------------------------------------------------- launch
extern "C" void kernel_launch(void* const* d_in, const int* in_sizes, int n_in,
                              void* d_out, int out_size, void* d_ws, size_t ws_size,
                              hipStream_t stream)
{
  const float* Lre    = (const float*)d_in[0];
  const float* Lim    = (const float*)d_in[1];
  const float* Pre    = (const float*)d_in[2];
  const float* Pim    = (const float*)d_in[3];
  const float* Bre    = (const float*)d_in[4];
  const float* Bim    = (const float*)d_in[5];
  const float* log_dt = (const float*)d_in[6];
  const float* Din    = (const float*)d_in[7];
  float* out = (float*)d_out;
  char* ws = (char*)d_ws;

  hipLaunchKernelGGL(precompute_kernel, dim3(64), dim3(256), 0, stream,
                     Lre, Lim, Pre, Pim, Bre, Bim, log_dt, ws);

  if (ws_size >= WS_NEED) {
    hipLaunchKernelGGL(cauchyfft_kernel, dim3(DMODEL * 4), dim3(512), 0, stream,
                       (const float4*)(ws + OFF_DN), (const float*)(ws + OFF_CDT),
                       (const float2*)(ws + OFF_TW), (float2*)(ws + OFF_XY));
    hipLaunchKernelGGL(finish_kernel, dim3(DMODEL * 8), dim3(256), 0, stream,
                       (const float2*)(ws + OFF_XY), (const float2*)(ws + OFF_TW),
                       Din, out);
  } else {
    hipLaunchKernelGGL(fused_kernel, dim3(DMODEL), dim3(1024), 0, stream,
                       (const float4*)(ws + OFF_DN), (const float*)(ws + OFF_CDT),
                       (const float2*)(ws + OFF_TW), Din, out);
  }
}